// Round 5
// baseline (344.478 us; speedup 1.0000x reference)
//
#include <hip/hip_runtime.h>
#include <hip/hip_bf16.h>
#include <math.h>

#define LSEQ 32768
#define HF   512
#define PS   128      // state_size/2
#define TWOP 256      // 2*PS (interleaved re,im)
#define NC   512      // scan chunks
#define CL   64       // chunk length  (NC*CL == LSEQ)

typedef __attribute__((ext_vector_type(8))) short short8v;   // 8 bf16 (4 VGPRs)
typedef __attribute__((ext_vector_type(4))) float f32x4;     // MFMA acc

// ---------------- helpers ----------------
__device__ __forceinline__ float sig_fast(float z) {
    // 1/(1+e^-z) via native exp + rcp (bf16-level accuracy downstream)
    return __builtin_amdgcn_rcpf(1.0f + __expf(-z));
}
__device__ __forceinline__ float gelu_fast(float v) {
    // tanh-gelu == v * sigmoid(2*0.79788456*(v + 0.044715 v^3))
    float z = 1.5957691216057308f * v * fmaf(0.044715f, v * v, 1.0f);
    return v * sig_fast(z);
}
__device__ __forceinline__ unsigned short bf16bits(float f) {
    __hip_bfloat16 h = __float2bfloat16(f);
    return *(unsigned short*)&h;
}
__device__ __forceinline__ float bf2f(unsigned short u) {
    unsigned v = ((unsigned)u) << 16;
    return *(float*)&v;
}
__device__ __forceinline__ void gload_lds16(const void* g, void* l) {
    __builtin_amdgcn_global_load_lds(
        (const __attribute__((address_space(1))) unsigned int*)g,
        (__attribute__((address_space(3))) unsigned int*)l, 16, 0, 0);
}

// ---------------- param prep ----------------
__global__ __launch_bounds__(128) void prep_lam_k(
    const float* __restrict__ lr_, const float* __restrict__ li_,
    const float* __restrict__ delta, float* lam, float* bls, float* lamPow)
{
    int p = threadIdx.x;
    float lr = lr_[p], li = li_[p];
    float step = expf(delta[p]);
    float s2 = 0.5f * step;
    float dr = 1.0f - s2 * lr, di = -s2 * li;
    float inv = 1.0f / (dr * dr + di * di);
    float blr = dr * inv, bli = -di * inv;
    float nr = 1.0f + s2 * lr, ni = s2 * li;
    float lbr = blr * nr - bli * ni;
    float lbi = blr * ni + bli * nr;
    lam[2 * p] = lbr; lam[2 * p + 1] = lbi;
    bls[2 * p] = blr * step; bls[2 * p + 1] = bli * step;
    float pr = 1.0f, pim = 0.0f;
    lamPow[2 * p] = 1.0f; lamPow[2 * p + 1] = 0.0f;
    for (int k = 1; k <= CL; k++) {
        float t = pr * lbr - pim * lbi;
        pim = pr * lbi + pim * lbr;
        pr = t;
        lamPow[k * TWOP + 2 * p] = pr;
        lamPow[k * TWOP + 2 * p + 1] = pim;
    }
}

// BwT[n=2p(+1)][h] bf16: pre-transposed B_bar (B'[N][K], K-contiguous)
__global__ __launch_bounds__(256) void prep_B_k(
    const float* __restrict__ b, const float* __restrict__ bls,
    unsigned short* __restrict__ bwt)
{
    int idx = blockIdx.x * 256 + threadIdx.x;   // over P*H
    int p = idx >> 9, h = idx & 511;
    float2 bb = *(const float2*)(b + ((size_t)p * HF + h) * 2);
    float sr = bls[2 * p], si = bls[2 * p + 1];
    bwt[(size_t)(2 * p) * HF + h]     = bf16bits(sr * bb.x - si * bb.y);
    bwt[(size_t)(2 * p + 1) * HF + h] = bf16bits(sr * bb.y + si * bb.x);
}

// CwT[h][2p(+1)] bf16: [N=H][K=2P] K-contiguous
__global__ __launch_bounds__(256) void prep_C_k(
    const float* __restrict__ c, unsigned short* __restrict__ cwt)
{
    int idx = blockIdx.x * 256 + threadIdx.x;   // over H*P
    int h = idx >> 7, p = idx & 127;
    float2 cc = *(const float2*)(c + ((size_t)h * PS + p) * 2);
    unsigned pk = ((unsigned)bf16bits(-2.0f * cc.y) << 16) | bf16bits(2.0f * cc.x);
    *(unsigned*)(cwt + (size_t)h * TWOP + 2 * p) = pk;
}

// w2T[n][k] bf16 = w2[k][n]
__global__ __launch_bounds__(256) void prep_w2_k(
    const float* __restrict__ w2, unsigned short* __restrict__ w2t)
{
    int idx = blockIdx.x * 256 + threadIdx.x;   // over H*H
    int n = idx >> 9, k = idx & 511;
    w2t[(size_t)n * HF + k] = bf16bits(w2[(size_t)k * HF + n]);
}

// ---------------- LayerNorm (bf16 out only) ----------------
__global__ __launch_bounds__(128) void ln_k(
    const float* __restrict__ x, const float* __restrict__ scale,
    const float* __restrict__ offs, unsigned short* __restrict__ xnbf)
{
    int row = blockIdx.x, t = threadIdx.x;
    const float4* xr = (const float4*)(x + (size_t)row * HF);
    float4 v = xr[t];
    float s = v.x + v.y + v.z + v.w;
    float q = v.x * v.x + v.y * v.y + v.z * v.z + v.w * v.w;
    #pragma unroll
    for (int off = 32; off > 0; off >>= 1) {
        s += __shfl_down(s, off);
        q += __shfl_down(q, off);
    }
    __shared__ float ss[2], qq[2];
    if ((t & 63) == 0) { ss[t >> 6] = s; qq[t >> 6] = q; }
    __syncthreads();
    float S = ss[0] + ss[1], Q = qq[0] + qq[1];
    float mean = S * (1.0f / HF);
    float var = Q * (1.0f / HF) - mean * mean;
    float rstd = rsqrtf(var + 1e-5f);
    float4 sc = ((const float4*)scale)[t];
    float4 of = ((const float4*)offs)[t];
    ushort4 hv;
    hv.x = bf16bits((v.x - mean) * rstd * sc.x + of.x);
    hv.y = bf16bits((v.y - mean) * rstd * sc.y + of.y);
    hv.z = bf16bits((v.z - mean) * rstd * sc.z + of.z);
    hv.w = bf16bits((v.w - mean) * rstd * sc.w + of.w);
    ((ushort4*)(xnbf + (size_t)row * HF))[t] = hv;
}

// ---------------- fused GEMM1 + local scan ----------------
// Bu-tile = xn * B_bar^T (128x128, K=512), then per-column local scan over the
// 2 chunks (64 rows each) inside the tile, emitting chunk finals F and the
// locally-scanned xs (fp32).
__global__ __launch_bounds__(256) void g1scan_k(
    const unsigned short* __restrict__ A,   // XNBF [L][HF]
    const unsigned short* __restrict__ Bt,  // BWT  [TWOP][HF]
    float* __restrict__ xs,                 // B1   [L][TWOP]
    float* __restrict__ F,                  // [NC][TWOP]
    const float* __restrict__ lam)
{
    __shared__ float yt[128 * 128];         // 64KB; first 16KB doubles as staging
    unsigned short* As = (unsigned short*)yt;            // 128*32 bf16
    unsigned short* Bs = (unsigned short*)yt + 128 * 32; // 128*32 bf16
    const int K = HF;
    const int bm = blockIdx.y << 7;
    const int bn = blockIdx.x << 7;
    const int tid = threadIdx.x;
    const int lane = tid & 63;
    const int wid = tid >> 6;
    const int wr = wid >> 1, wc = wid & 1;

    f32x4 acc[4][4] = {};

    const int r0 = (wid << 5) + (lane >> 2);
    const int c0 = (lane & 3) << 3;
    const unsigned short* gA = A + (size_t)(bm + r0) * K + c0;
    const unsigned short* gB = Bt + (size_t)(bn + r0) * K + c0;
    unsigned short* lA0 = As + (wid << 5) * 32;
    unsigned short* lA1 = As + ((wid << 5) + 16) * 32;
    unsigned short* lB0 = Bs + (wid << 5) * 32;
    unsigned short* lB1 = Bs + ((wid << 5) + 16) * 32;
    const int aoff = ((wr << 6) + (lane & 15)) * 32 + ((lane >> 4) << 3);
    const int boff = ((wc << 6) + (lane & 15)) * 32 + ((lane >> 4) << 3);

    for (int k0 = 0; k0 < K; k0 += 32) {
        gload_lds16(gA + k0, lA0);
        gload_lds16(gA + k0 + (size_t)16 * K, lA1);
        gload_lds16(gB + k0, lB0);
        gload_lds16(gB + k0 + (size_t)16 * K, lB1);
        __syncthreads();
        short8v a[4], b[4];
        #pragma unroll
        for (int m = 0; m < 4; m++)
            a[m] = *(const short8v*)(As + aoff + (m << 4) * 32);
        #pragma unroll
        for (int n = 0; n < 4; n++)
            b[n] = *(const short8v*)(Bs + boff + (n << 4) * 32);
        #pragma unroll
        for (int m = 0; m < 4; m++)
            #pragma unroll
            for (int n = 0; n < 4; n++)
                acc[m][n] = __builtin_amdgcn_mfma_f32_16x16x32_bf16(
                    a[m], b[n], acc[m][n], 0, 0, 0);
        __syncthreads();
    }

    // acc -> LDS tile (row-major [128][128])
    #pragma unroll
    for (int m = 0; m < 4; m++) {
        const int rowb = (wr << 6) + (m << 4) + ((lane >> 4) << 2);
        #pragma unroll
        for (int n = 0; n < 4; n++) {
            const int col = (wc << 6) + (n << 4) + (lane & 15);
            #pragma unroll
            for (int j = 0; j < 4; j++)
                yt[(rowb + j) * 128 + col] = acc[m][n][j];
        }
    }
    __syncthreads();

    // local scan: 128 threads, each owns (chunk, complex pair)
    if (tid < 128) {
        int ch = tid >> 6, q = tid & 63;
        int pg = (blockIdx.x << 6) + q;          // global pair index
        float lr = lam[2 * pg], liv = lam[2 * pg + 1];
        float sr = 0.0f, si = 0.0f;
        float* col = yt + (ch << 6) * 128 + 2 * q;
        #pragma unroll 8
        for (int i = 0; i < CL; i++) {
            float ur = col[i * 128], ui = col[i * 128 + 1];
            float tr = lr * sr - liv * si + ur;
            float ti = lr * si + liv * sr + ui;
            sr = tr; si = ti;
            col[i * 128] = sr; col[i * 128 + 1] = si;
        }
        int cg = (blockIdx.y << 1) + ch;
        F[(size_t)cg * TWOP + (blockIdx.x << 7) + 2 * q] = sr;
        F[(size_t)cg * TWOP + (blockIdx.x << 7) + 2 * q + 1] = si;
    }
    __syncthreads();

    // write tile to global xs (coalesced float4)
    #pragma unroll
    for (int j = 0; j < 16; j++) {
        int fl = j * 256 + tid;          // float4 index within tile
        int r = fl >> 5, c4 = fl & 31;
        float4 v = *(float4*)&yt[r * 128 + c4 * 4];
        *(float4*)(xs + (size_t)(bm + r) * TWOP + bn + c4 * 4) = v;
    }
}

// ---------------- scan pass 2/3 ----------------
__global__ __launch_bounds__(128) void scan2_k(
    const float* __restrict__ F, float* __restrict__ G, const float* __restrict__ lamPow)
{
    int p = threadIdx.x;
    float lr = lamPow[CL * TWOP + 2 * p], li = lamPow[CL * TWOP + 2 * p + 1]; // lam^CL
    float gr = 0.0f, gi = 0.0f;
    for (int c = 0; c < NC; c++) {
        float2 f = *(const float2*)(F + (size_t)c * TWOP + 2 * p);
        float tr = lr * gr - li * gi + f.x;
        float ti = lr * gi + li * gr + f.y;
        gr = tr; gi = ti;
        *(float2*)(G + (size_t)c * TWOP + 2 * p) = make_float2(gr, gi);
    }
}

__global__ __launch_bounds__(128) void scan3_k(
    const float* __restrict__ xs, const float* __restrict__ G,
    const float* __restrict__ lamPow, unsigned short* __restrict__ xsbf)
{
    int c = blockIdx.x, p = threadIdx.x;
    float crr = 0.0f, cri = 0.0f;
    if (c > 0) {
        float2 g = *(const float2*)(G + (size_t)(c - 1) * TWOP + 2 * p);
        crr = g.x; cri = g.y;
    }
    size_t base = (size_t)c * CL * TWOP + 2 * p;
    for (int i = 0; i < CL; i++) {
        float2 v = *(const float2*)(xs + base + (size_t)i * TWOP);
        float2 lp = *(const float2*)(lamPow + (size_t)(i + 1) * TWOP + 2 * p);
        v.x += lp.x * crr - lp.y * cri;
        v.y += lp.x * cri + lp.y * crr;
        unsigned pk = ((unsigned)bf16bits(v.y) << 16) | bf16bits(v.x);
        *(unsigned*)(xsbf + base + (size_t)i * TWOP) = pk;
    }
}

// ---------------- bf16 MFMA GEMM (m97 structure) ----------------
// MODE 1: y = acc + e0[col]*bf2f(e1h[off]); C=y fp32; obf = bf16(gelu(y))
//         (e1h = bf16 xn; obf overwrites e1h in place, same off per thread)
// MODE 2: C = e2[off] + e1f[off]*sigmoid(acc + e0[col])
template<int MODE>
__global__ __launch_bounds__(256) void mgemm_k(
    const unsigned short* __restrict__ A, const unsigned short* __restrict__ Bt,
    float* __restrict__ C, int K, int N,
    const float* __restrict__ e0, const void* e1,
    const float* __restrict__ e2, unsigned short* __restrict__ obf)
{
    __shared__ unsigned short As[128 * 32];
    __shared__ unsigned short Bs[128 * 32];
    const int bm = blockIdx.y << 7;
    const int bn = blockIdx.x << 7;
    const int tid = threadIdx.x;
    const int lane = tid & 63;
    const int wid = tid >> 6;
    const int wr = wid >> 1, wc = wid & 1;

    f32x4 acc[4][4] = {};

    const int r0 = (wid << 5) + (lane >> 2);
    const int c0 = (lane & 3) << 3;
    const unsigned short* gA = A + (size_t)(bm + r0) * K + c0;
    const unsigned short* gB = Bt + (size_t)(bn + r0) * K + c0;
    unsigned short* lA0 = As + (wid << 5) * 32;
    unsigned short* lA1 = As + ((wid << 5) + 16) * 32;
    unsigned short* lB0 = Bs + (wid << 5) * 32;
    unsigned short* lB1 = Bs + ((wid << 5) + 16) * 32;
    const int aoff = ((wr << 6) + (lane & 15)) * 32 + ((lane >> 4) << 3);
    const int boff = ((wc << 6) + (lane & 15)) * 32 + ((lane >> 4) << 3);

    for (int k0 = 0; k0 < K; k0 += 32) {
        gload_lds16(gA + k0, lA0);
        gload_lds16(gA + k0 + (size_t)16 * K, lA1);
        gload_lds16(gB + k0, lB0);
        gload_lds16(gB + k0 + (size_t)16 * K, lB1);
        __syncthreads();
        short8v a[4], b[4];
        #pragma unroll
        for (int m = 0; m < 4; m++)
            a[m] = *(const short8v*)(As + aoff + (m << 4) * 32);
        #pragma unroll
        for (int n = 0; n < 4; n++)
            b[n] = *(const short8v*)(Bs + boff + (n << 4) * 32);
        #pragma unroll
        for (int m = 0; m < 4; m++)
            #pragma unroll
            for (int n = 0; n < 4; n++)
                acc[m][n] = __builtin_amdgcn_mfma_f32_16x16x32_bf16(
                    a[m], b[n], acc[m][n], 0, 0, 0);
        __syncthreads();
    }

    const unsigned short* e1h = (const unsigned short*)e1;
    const float* e1f = (const float*)e1;
    #pragma unroll
    for (int m = 0; m < 4; m++) {
        const int rowb = bm + (wr << 6) + (m << 4) + ((lane >> 4) << 2);
        #pragma unroll
        for (int n = 0; n < 4; n++) {
            const int col = bn + (wc << 6) + (n << 4) + (lane & 15);
            const float e0v = e0 ? e0[col] : 0.0f;
            #pragma unroll
            for (int j = 0; j < 4; j++) {
                const size_t off = (size_t)(rowb + j) * N + col;
                float v = acc[m][n][j];
                if (MODE == 1) {
                    float y = v + e0v * bf2f(e1h[off]);
                    C[off] = y;
                    obf[off] = bf16bits(gelu_fast(y));
                } else {
                    C[off] = e2[off] + e1f[off] * sig_fast(v + e0v);
                }
            }
        }
    }
}

// ---------------- launch ----------------
extern "C" void kernel_launch(void* const* d_in, const int* in_sizes, int n_in,
                              void* d_out, int out_size, void* d_ws, size_t ws_size,
                              hipStream_t stream)
{
    const float* x      = (const float*)d_in[0];
    const float* lr     = (const float*)d_in[1];
    const float* li     = (const float*)d_in[2];
    const float* b      = (const float*)d_in[3];
    const float* c      = (const float*)d_in[4];
    const float* d      = (const float*)d_in[5];
    const float* delta  = (const float*)d_in[6];
    const float* nsc    = (const float*)d_in[7];
    const float* noff   = (const float*)d_in[8];
    const float* w2     = (const float*)d_in[9];
    const float* b2     = (const float*)d_in[10];
    float* out = (float*)d_out;

    float* X1 = (float*)d_ws;                           // [L,H] fp32: y
    float* B1 = X1 + (size_t)LSEQ * HF;                 // [L,2P] fp32: local xs
    unsigned short* XNBF = (unsigned short*)(B1 + (size_t)LSEQ * TWOP); // [L,H] bf16: xn -> x1
    unsigned short* XSBF = XNBF + (size_t)LSEQ * HF;    // [L,2P] bf16: xs
    unsigned short* BWT  = XSBF + (size_t)LSEQ * TWOP;  // [2P,H] bf16
    unsigned short* CWT  = BWT + (size_t)TWOP * HF;     // [H,2P] bf16
    unsigned short* W2T  = CWT + (size_t)HF * TWOP;     // [H,H] bf16
    float* lam    = (float*)(W2T + (size_t)HF * HF);
    float* bls    = lam + TWOP;
    float* lamPow = bls + TWOP;                         // [(CL+1),2P]
    float* F      = lamPow + (size_t)(CL + 1) * TWOP;   // [NC,2P]
    float* G      = F + (size_t)NC * TWOP;              // [NC,2P]

    // params
    prep_lam_k<<<1, 128, 0, stream>>>(lr, li, delta, lam, bls, lamPow);
    prep_B_k<<<(PS * HF) / 256, 256, 0, stream>>>(b, bls, BWT);
    prep_C_k<<<(HF * PS) / 256, 256, 0, stream>>>(c, CWT);
    prep_w2_k<<<(HF * HF) / 256, 256, 0, stream>>>(w2, W2T);
    // layernorm -> bf16 xn
    ln_k<<<LSEQ, 128, 0, stream>>>(x, nsc, noff, XNBF);
    // Bu = xn * B_bar^T fused with local scan  [L,512]x[512,256]
    g1scan_k<<<dim3(TWOP >> 7, LSEQ >> 7), 256, 0, stream>>>(
        XNBF, BWT, B1, F, lam);
    // carry scan + broadcast
    scan2_k<<<1, 128, 0, stream>>>(F, G, lamPow);
    scan3_k<<<NC, 128, 0, stream>>>(B1, G, lamPow, XSBF);
    // y = xs*Cw + d*xn; writes y fp32 + bf16 gelu(y) (over xn)
    mgemm_k<1><<<dim3(HF >> 7, LSEQ >> 7), 256, 0, stream>>>(
        XSBF, CWT, X1, TWOP, HF, d, XNBF, nullptr, XNBF);
    // out = x + y*sigmoid(x1@w2 + b2)
    mgemm_k<2><<<dim3(HF >> 7, LSEQ >> 7), 256, 0, stream>>>(
        XNBF, W2T, out, HF, HF, b2, X1, x, nullptr);
}